// Round 6
// baseline (2474.602 us; speedup 1.0000x reference)
//
#include <hip/hip_runtime.h>
#include <hip/hip_bf16.h>
#include <math.h>

#define HD 128
#define NN 512
#define BBATCH 4
#define JT 32
#define APITCH 384            // bytes per staged-tile row: 256 Bp + 64 rbf/1/zero + pad

typedef __attribute__((ext_vector_type(8))) short bf16x8;
typedef __attribute__((ext_vector_type(4))) float f32x4;
typedef unsigned int uint;
typedef unsigned short ushort;

#define MFMA16 __builtin_amdgcn_mfma_f32_16x16x32_bf16

__device__ __forceinline__ float silu_f(float v) {
    float e = __expf(-v);
    return v * __builtin_amdgcn_rcpf(1.f + e);
}

__device__ __forceinline__ short f2bf(float v) {
    union { __hip_bfloat16 h; short s; } u;
    u.h = __float2bfloat16(v);
    return u.s;
}

// ---------------- time MLP: t -> t_emb (B,128) ----------------
__global__ void k_time(const float* __restrict__ t,
                       const float* __restrict__ w1, const float* __restrict__ b1,
                       const float* __restrict__ w2, const float* __restrict__ b2,
                       float* __restrict__ t_emb) {
    int b = blockIdx.x;
    int h = threadIdx.x;           // 0..127
    __shared__ float te[64];
    __shared__ float hid[128];
    float tv = t[b];
    if (h < 32) {
        const float cst = (float)(-2.302585092994046 * 4.0 / 31.0); // -ln(10000)/31
        float freq = __expf((float)h * cst);
        float ang = tv * freq;
        te[h]      = sinf(ang);
        te[h + 32] = cosf(ang);
    }
    __syncthreads();
    float acc = b1[h];
    #pragma unroll 8
    for (int k = 0; k < 64; ++k) acc += te[k] * w1[k * HD + h];
    hid[h] = silu_f(acc);
    __syncthreads();
    float acc2 = b2[h];
    #pragma unroll 8
    for (int k = 0; k < HD; ++k) acc2 += hid[k] * w2[k * HD + h];
    t_emb[b * HD + h] = acc2;
}

// ---------------- broadcast t_emb -> h (B,N,H) ----------------
__global__ void k_bcast(const float* __restrict__ t_emb, float* __restrict__ h) {
    int idx = blockIdx.x * 256 + threadIdx.x;   // B*N*H = 262144
    int hch = idx & 127;
    int b = idx >> 16;                           // N*H = 65536
    h[idx] = t_emb[b * HD + hch];
}

// ---------------- per-node projections: A = h@W1_top + b1 (f32), Bp = h@W1_mid (bf16)
__global__ void k_proj(const float* __restrict__ h,
                       const float* __restrict__ w1,   // (272,128) of this layer
                       const float* __restrict__ b1,
                       float* __restrict__ A, ushort* __restrict__ Bpb) {
    int node = blockIdx.x;       // b*N+i, 2048 total
    int hc = threadIdx.x;        // 0..127
    __shared__ float hrow[HD];
    hrow[hc] = h[node * HD + hc];
    __syncthreads();
    float a = b1[hc];
    float bb = 0.f;
    #pragma unroll 8
    for (int k = 0; k < HD; ++k) {
        a  += hrow[k] * w1[k * HD + hc];
        bb += hrow[k] * w1[(HD + k) * HD + hc];
    }
    A[node * HD + hc] = a;
    Bpb[node * HD + hc] = (ushort)f2bf(bb);
}

// ---------------- MFMA edge kernel (R3 structure + Bp-hoist) ----------------
// block = 256 = 4 waves; block <-> node i; 32 j's per iteration (16 iters).
// Staged tile row (384 B): [Bp_j bf16 x128 | rbf bf16 x16 | 1.0 | zeros].
// ph2: preact = [rbf|1] @ [W1r;A_i] (K=32 MFMA, the k=128..159 block) + Bp_j.
__global__ __launch_bounds__(256, 3)
void k_edge(const float* __restrict__ x,
            const float* __restrict__ h_in, float* __restrict__ h_out,
            const float* __restrict__ A, const ushort* __restrict__ Bpb,
            const float* __restrict__ w1r,   // (16,128) rbf rows of msg_w1[l]
            const float* __restrict__ w2,    // (128,128)
            const float* __restrict__ b2,
            const float* __restrict__ cw1,   // (128,128)
            const float* __restrict__ cb1,
            const float* __restrict__ cw2,   // (128)
            const float* __restrict__ cb2,   // (1)
            float* __restrict__ out) {
    __shared__ uint4 sAq[2][JT * (APITCH / 16)];    // 2 x 12 KB
    __shared__ uint4 sMAq[JT * 16];                 // 8 KB  [32][256B]
    __shared__ uint4 sMMq[JT * 16];                 // 8 KB
    __shared__ __align__(16) float sPart[JT * 68];  // [32][272B]
    __shared__ float sDir[2][JT][3];
    __shared__ float sMask[2][JT];
    __shared__ float sHS[HD];
    __shared__ float sCA[JT][3];

    const int tid = threadIdx.x;
    const int l  = tid & 63;
    const int w  = tid >> 6;            // wave 0..3
    const int lg = l >> 4;              // lane k-group 0..3
    const int ln = l & 15;
    const int nb = w * 32;
    const int n0 = nb + ln;
    const int n1 = n0 + 16;
    const int node = blockIdx.x;        // b*N + i
    const int b = node >> 9;
    const float* __restrict__ xb = x + (size_t)b * NN * 3;
    const ushort* __restrict__ BpbN = Bpb + (size_t)b * NN * HD;

    // ---- per-lane constants ----
    const float bb20 = b2[n0], bb21 = b2[n1];
    const float cb10 = cb1[n0], cb11 = cb1[n1];
    const float cwv0 = cw2[n0], cwv1 = cw2[n1];
    const float cb2v = cb2[0];
    const float xi0 = x[node * 3 + 0], xi1 = x[node * 3 + 1], xi2 = x[node * 3 + 2];
    const float cstep = 10.f / 15.f;
    const float rbfk = 1.28f;

    // ---- weight fragments (single bf16) ----
    bf16x8 wR[2], w2f[2][4], c1f[2][4];
    #pragma unroll
    for (int nt = 0; nt < 2; ++nt) {
        int n = nb + nt * 16 + ln;
        #pragma unroll
        for (int ks = 0; ks < 4; ++ks) {
            #pragma unroll
            for (int i = 0; i < 8; ++i) {
                int k = ks * 32 + lg * 8 + i;
                w2f[nt][ks][i] = f2bf(w2[k * HD + n]);
                c1f[nt][ks][i] = f2bf(cw1[k * HD + n]);
            }
        }
        #pragma unroll
        for (int i = 0; i < 8; ++i) {
            int kr = lg * 8 + i;
            float v = (kr < 16) ? w1r[kr * HD + n]
                    : (kr == 16 ? A[node * HD + n] : 0.f);
            wR[nt][i] = f2bf(v);
        }
    }

    // ---- init constant tile regions (k=144 "1", k=145..159 zeros), both buffers
    if (tid < 64) {
        char* base = (char*)sAq + (tid >> 5) * (JT * APITCH) + (tid & 31) * APITCH;
        int sw = ((tid & 7) << 4);
        *(uint*)(base + (288 ^ sw) + 0)  = 0x00003F80u;  // k144=1.0bf, k145=0
        *(uint*)(base + (288 ^ sw) + 4)  = 0u;
        *(uint*)(base + (288 ^ sw) + 8)  = 0u;
        *(uint*)(base + (288 ^ sw) + 12) = 0u;
        uint4 z4 = {0u, 0u, 0u, 0u};
        *(uint4*)(base + (304 ^ sw)) = z4;               // k152..159
    }

    const int hr = tid >> 4, hseg = tid & 15;
    const int jj = tid >> 3, rp = tid & 7;

    // ---- prologue: stage tile 0 ----
    {
        char* bufc = (char*)sAq;
        const ushort* src = BpbN + (size_t)hr * HD + hseg * 8;
        uint4 bv0 = *(const uint4*)src;
        uint4 bv1 = *(const uint4*)(src + 16 * HD);
        // geometry tile 0
        const float* xj = xb + jj * 3;
        float d0 = xj[0] - xi0, d1 = xj[1] - xi1, d2 = xj[2] - xi2;
        float d = sqrtf(d0 * d0 + d1 * d1 + d2 * d2);
        float c0 = (float)(rp * 2) * cstep;
        float e0 = __expf(-(d - c0) * (d - c0) * rbfk);
        float e1 = __expf(-(d - c0 - cstep) * (d - c0 - cstep) * rbfk);
        uint pk = (uint)(ushort)f2bf(e0) | ((uint)(ushort)f2bf(e1) << 16);
        *(uint*)(bufc + jj * APITCH + ((256 + (rp & 4) * 4) ^ ((jj & 7) << 4)) + (rp & 3) * 4) = pk;
        if (rp == 0) {
            float inv = __builtin_amdgcn_rcpf(d + 1e-8f);
            sDir[0][jj][0] = d0 * inv; sDir[0][jj][1] = d1 * inv; sDir[0][jj][2] = d2 * inv;
            sMask[0][jj] = (d < 10.f && d > 0.f) ? 1.f : 0.f;
        }
        int off = (hseg * 16) ^ ((hr & 7) << 4);
        *(uint4*)(bufc + hr * APITCH + off) = bv0;
        *(uint4*)(bufc + (hr + 16) * APITCH + off) = bv1;
    }
    float hreg0 = 0.f, hreg1 = 0.f;
    float ca0 = 0.f, ca1 = 0.f, ca2 = 0.f;
    __syncthreads();

    const int swA = (ln & 7) << 4;
    const int colb0 = nb * 2 + (ln & 8) * 2 + (ln & 7) * 2;          // byte of col n0 in row
    const int colb1 = (nb + 16) * 2 + (ln & 8) * 2 + (ln & 7) * 2;   // byte of col n1

    for (int it = 0; it <= 16; ++it) {
        // ---- ph5 (software-pipelined): edge weights of tile it-1 -> coord accum
        if (it > 0) {
            const int pm = (it - 1) & 1;
            const char* pp = (const char*)sPart + jj * 272;
            f32x4 pa = *(const f32x4*)(pp + ((jj & 7) << 4 ^ (rp * 32)));
            f32x4 pb = *(const f32x4*)(pp + ((jj & 7) << 4 ^ (rp * 32 + 16)));
            float s = pa[0] + pa[1] + pa[2] + pa[3] + pb[0] + pb[1] + pb[2] + pb[3];
            s += __shfl_xor(s, 1); s += __shfl_xor(s, 2); s += __shfl_xor(s, 4);
            if (rp == 0) {
                float wv = (s + cb2v) * sMask[pm][jj];
                ca0 += wv * sDir[pm][jj][0];
                ca1 += wv * sDir[pm][jj][1];
                ca2 += wv * sDir[pm][jj][2];
            }
        }
        if (it == 16) break;
        const int p = it & 1;

        // ---- stage + geometry for tile it+1 (issue loads early, write after ph2)
        uint4 bv0, bv1;
        if (it < 15) {
            const ushort* src = BpbN + (size_t)((it + 1) * JT + hr) * HD + hseg * 8;
            bv0 = *(const uint4*)src;
            bv1 = *(const uint4*)(src + 16 * HD);
            char* bufn = (char*)sAq + (p ^ 1) * (JT * APITCH);
            int j = (it + 1) * JT + jj;
            const float* xj = xb + j * 3;
            float d0 = xj[0] - xi0, d1 = xj[1] - xi1, d2 = xj[2] - xi2;
            float d = sqrtf(d0 * d0 + d1 * d1 + d2 * d2);
            float c0 = (float)(rp * 2) * cstep;
            float e0 = __expf(-(d - c0) * (d - c0) * rbfk);
            float e1 = __expf(-(d - c0 - cstep) * (d - c0 - cstep) * rbfk);
            uint pk = (uint)(ushort)f2bf(e0) | ((uint)(ushort)f2bf(e1) << 16);
            *(uint*)(bufn + jj * APITCH + ((256 + (rp & 4) * 4) ^ ((jj & 7) << 4)) + (rp & 3) * 4) = pk;
            if (rp == 0) {
                float inv = __builtin_amdgcn_rcpf(d + 1e-8f);
                sDir[p ^ 1][jj][0] = d0 * inv; sDir[p ^ 1][jj][1] = d1 * inv; sDir[p ^ 1][jj][2] = d2 * inv;
                sMask[p ^ 1][jj] = (d < 10.f && d > 0.f) ? 1.f : 0.f;
            }
        }

        // ---- ph2: preact = [rbf|1] @ [W1r;A_i] (K=32, k=128..159 block) + Bp_j ; silu -> sMA
        {
            const char* bufc = (const char*)sAq + p * (JT * APITCH);
            f32x4 zz = {0.f, 0.f, 0.f, 0.f};
            #pragma unroll
            for (int mt = 0; mt < 2; ++mt) {
                const char* rowp = bufc + (ln + mt * 16) * APITCH;
                bf16x8 af4 = *(const bf16x8*)(rowp + ((256 + lg * 16) ^ swA));
                f32x4 p0 = MFMA16(af4, wR[0], zz, 0, 0, 0);
                f32x4 p1 = MFMA16(af4, wR[1], zz, 0, 0, 0);
                #pragma unroll
                for (int reg = 0; reg < 4; ++reg) {
                    int j = mt * 16 + lg * 4 + reg;
                    int sw = (j & 7) << 4;
                    const char* brow = bufc + j * APITCH;
                    uint u0 = *(const ushort*)(brow + (colb0 ^ sw));
                    uint u1 = *(const ushort*)(brow + (colb1 ^ sw));
                    float v0 = silu_f(p0[reg] + __uint_as_float(u0 << 16));
                    float v1 = silu_f(p1[reg] + __uint_as_float(u1 << 16));
                    *(short*)((char*)sMAq + j * 256 + (colb0 ^ sw)) = f2bf(v0);
                    *(short*)((char*)sMAq + j * 256 + (colb1 ^ sw)) = f2bf(v1);
                }
            }
        }
        // ---- write staged Bp for tile it+1 (loads issued before ph2)
        if (it < 15) {
            char* bufn = (char*)sAq + (p ^ 1) * (JT * APITCH);
            int off = (hseg * 16) ^ ((hr & 7) << 4);
            *(uint4*)(bufn + hr * APITCH + off) = bv0;
            *(uint4*)(bufn + (hr + 16) * APITCH + off) = bv1;
        }
        __syncthreads();                 // B1: sMA + next tile staged

        // ---- ph3: MSG = MA @ W2 + b2 ; mask ; h-sum ; -> sMM
        {
            f32x4 macc[2][2];
            f32x4 i0 = {bb20, bb20, bb20, bb20};
            f32x4 i1 = {bb21, bb21, bb21, bb21};
            #pragma unroll
            for (int mt = 0; mt < 2; ++mt) {
                macc[mt][0] = i0; macc[mt][1] = i1;
                const char* rowp = (const char*)sMAq + (ln + mt * 16) * 256;
                bf16x8 am[4];
                #pragma unroll
                for (int ks = 0; ks < 4; ++ks)
                    am[ks] = *(const bf16x8*)(rowp + ((ks * 64 + lg * 16) ^ swA));
                #pragma unroll
                for (int ks = 0; ks < 4; ++ks) {
                    macc[mt][0] = MFMA16(am[ks], w2f[0][ks], macc[mt][0], 0, 0, 0);
                    macc[mt][1] = MFMA16(am[ks], w2f[1][ks], macc[mt][1], 0, 0, 0);
                }
            }
            #pragma unroll
            for (int mt = 0; mt < 2; ++mt)
                #pragma unroll
                for (int reg = 0; reg < 4; ++reg) {
                    int j = mt * 16 + lg * 4 + reg;
                    float msk = sMask[p][j];
                    float g0 = macc[mt][0][reg] * msk;
                    float g1 = macc[mt][1][reg] * msk;
                    hreg0 += g0; hreg1 += g1;
                    int sw = (j & 7) << 4;
                    *(short*)((char*)sMMq + j * 256 + (colb0 ^ sw)) = f2bf(g0);
                    *(short*)((char*)sMMq + j * 256 + (colb1 ^ sw)) = f2bf(g1);
                }
        }
        __syncthreads();                 // B2: sMM ready

        // ---- ph4: CH = silu(MM @ cw1 + cb1); partial dot with cw2 -> sPart
        {
            f32x4 cacc[2][2];
            f32x4 i0 = {cb10, cb10, cb10, cb10};
            f32x4 i1 = {cb11, cb11, cb11, cb11};
            #pragma unroll
            for (int mt = 0; mt < 2; ++mt) {
                cacc[mt][0] = i0; cacc[mt][1] = i1;
                const char* rowp = (const char*)sMMq + (ln + mt * 16) * 256;
                bf16x8 am[4];
                #pragma unroll
                for (int ks = 0; ks < 4; ++ks)
                    am[ks] = *(const bf16x8*)(rowp + ((ks * 64 + lg * 16) ^ swA));
                #pragma unroll
                for (int ks = 0; ks < 4; ++ks) {
                    cacc[mt][0] = MFMA16(am[ks], c1f[0][ks], cacc[mt][0], 0, 0, 0);
                    cacc[mt][1] = MFMA16(am[ks], c1f[1][ks], cacc[mt][1], 0, 0, 0);
                }
            }
            #pragma unroll
            for (int mt = 0; mt < 2; ++mt)
                #pragma unroll
                for (int reg = 0; reg < 4; ++reg) {
                    int j = mt * 16 + lg * 4 + reg;
                    float v = silu_f(cacc[mt][0][reg]) * cwv0 + silu_f(cacc[mt][1][reg]) * cwv1;
                    *(float*)((char*)sPart + j * 272 + (((w * 16 + ln) * 4) ^ ((j & 7) << 4))) = v;
                }
        }
        __syncthreads();                 // B3: sPart ready
    }

    // ---- epilogue: h_out ----
    float t0 = hreg0; t0 += __shfl_xor(t0, 16); t0 += __shfl_xor(t0, 32);
    float t1 = hreg1; t1 += __shfl_xor(t1, 16); t1 += __shfl_xor(t1, 32);
    if (l < 16) { sHS[n0] = t0; sHS[n1] = t1; }
    if (rp == 0) { sCA[jj][0] = ca0; sCA[jj][1] = ca1; sCA[jj][2] = ca2; }
    __syncthreads();
    if (tid < HD) h_out[node * HD + tid] = h_in[node * HD + tid] + sHS[tid];
    if (tid < 3) {
        float s = 0.f;
        #pragma unroll
        for (int q = 0; q < JT; ++q) s += sCA[q][tid];
        out[node * 3 + tid] += s;
    }
}

extern "C" void kernel_launch(void* const* d_in, const int* in_sizes, int n_in,
                              void* d_out, int out_size, void* d_ws, size_t ws_size,
                              hipStream_t stream) {
    const float* x   = (const float*)d_in[0];
    const float* t   = (const float*)d_in[1];
    const float* tw1 = (const float*)d_in[2];
    const float* tb1 = (const float*)d_in[3];
    const float* tw2 = (const float*)d_in[4];
    const float* tb2 = (const float*)d_in[5];
    const float* mw1 = (const float*)d_in[6];
    const float* mb1 = (const float*)d_in[7];
    const float* mw2 = (const float*)d_in[8];
    const float* mb2 = (const float*)d_in[9];
    const float* cw1 = (const float*)d_in[10];
    const float* cb1 = (const float*)d_in[11];
    const float* cw2 = (const float*)d_in[12];
    const float* cb2 = (const float*)d_in[13];
    float* out = (float*)d_out;
    float* ws = (float*)d_ws;

    float* t_emb = ws;                          // 512
    float* h0 = ws + 512;                       // 262144
    float* h1 = h0 + 262144;                    // 262144
    float* Abuf = h1 + 262144;                  // 262144
    ushort* Bpb = (ushort*)(Abuf + 262144);     // 262144 ushort

    hipMemsetAsync(d_out, 0, (size_t)out_size * sizeof(float), stream);
    k_time<<<BBATCH, 128, 0, stream>>>(t, tw1, tb1, tw2, tb2, t_emb);
    k_bcast<<<(BBATCH * NN * HD) / 256, 256, 0, stream>>>(t_emb, h0);

    float* hc = h0;
    float* hn = h1;
    for (int l = 0; l < 4; ++l) {
        k_proj<<<BBATCH * NN, 128, 0, stream>>>(hc, mw1 + (size_t)l * 272 * 128,
                                                mb1 + l * 128, Abuf, Bpb);
        k_edge<<<BBATCH * NN, 256, 0, stream>>>(
            x, hc, hn, Abuf, Bpb,
            mw1 + (size_t)l * 272 * 128 + 256 * 128,
            mw2 + (size_t)l * 128 * 128, mb2 + l * 128,
            cw1 + (size_t)l * 128 * 128, cb1 + l * 128,
            cw2 + l * 128, cb2 + l, out);
        float* tf = hc; hc = hn; hn = tf;
    }
}